// Round 2
// baseline (94.504 us; speedup 1.0000x reference)
//
#include <hip/hip_runtime.h>

// loss = sum over flows/channels of mean_{b,h,w} || (I - P_A) patch ||^2
// P_A = affine projector over patch offsets (a,c); coordinate grids are affine
// -> annihilated, so only raw flow matters.
// r = sumsq - sum^2/kz^2 - (sa^2+sc^2)/S,  S = kz * sum_t (t-m)^2, m=(kz-1)/2.
//
// Single fused kernel: blocks [0,NB0) -> flow0 (kz=3, 2-pixel strips),
// blocks [NB0,NB0+NB1) -> flow1 (kz=5, 4-pixel strips). Per-block atomicAdd
// into d_out (zeroed by a 4-byte memset node).

#define NB0 256
#define NB1 1792

__global__ __launch_bounds__(256) void fused_affine_loss_kernel(
    const float* __restrict__ f0, const float* __restrict__ f1,
    float* __restrict__ out) {
    float acc = 0.f;

    if (blockIdx.x < NB0) {
        // flow0: (64, 128, 128), kz=3, Wout=126. 2-pixel strips: 63 strips/row.
        constexpr int W = 128, ROWS = 126, SPR = 63;
        constexpr int NST = 64 * ROWS * SPR;          // 508032 strips
        const float invk2 = 1.f / 9.f;
        const float invS  = 1.f / 6.f;                // kz * sum (t-1)^2 = 3*2
        for (int idx = blockIdx.x * 256 + threadIdx.x; idx < NST;
             idx += NB0 * 256) {
            int si = idx % SPR;
            int t  = idx / SPR;
            int y  = t % ROWS;
            int bc = t / ROWS;
            const float* base = f0 + (size_t)bc * (W * W) + y * W + si * 2;

            float sum0 = 0.f, sq0 = 0.f, sa0 = 0.f, sc0 = 0.f;
            float sum1 = 0.f, sq1 = 0.f, sa1 = 0.f, sc1 = 0.f;
#pragma unroll
            for (int a = 0; a < 3; ++a) {
                const float* r = base + a * W;
                float2 u = *(const float2*)r;        // 8B-aligned
                float2 v = *(const float2*)(r + 2);
                float p0 = u.x, p1 = u.y, p2 = v.x, p3 = v.y;
                float rs0 = p0 + p1 + p2, rs1 = p1 + p2 + p3;
                float rq0 = p0 * p0 + p1 * p1 + p2 * p2;
                float rq1 = p1 * p1 + p2 * p2 + p3 * p3;
                float aw = (float)(a - 1);
                sum0 += rs0; sq0 += rq0; sa0 += aw * rs0; sc0 += p2 - p0;
                sum1 += rs1; sq1 += rq1; sa1 += aw * rs1; sc1 += p3 - p1;
            }
            acc += sq0 - sum0 * sum0 * invk2 - (sa0 * sa0 + sc0 * sc0) * invS;
            acc += sq1 - sum1 * sum1 * invk2 - (sa1 * sa1 + sc1 * sc1) * invS;
        }
        acc *= 1.0f / (32.0f * 126.0f * 126.0f);
    } else {
        // flow1: (64, 256, 256), kz=5, Wout=252. 4-pixel strips: 63 strips/row.
        constexpr int W = 256, ROWS = 252, SPR = 63;
        constexpr int NST = 64 * ROWS * SPR;          // 1016064 strips
        const float invk2 = 1.f / 25.f;
        const float invS  = 1.f / 50.f;               // 5 * (4+1+0+1+4)
        for (int idx = (blockIdx.x - NB0) * 256 + threadIdx.x; idx < NST;
             idx += NB1 * 256) {
            int si = idx % SPR;
            int t  = idx / SPR;
            int y  = t % ROWS;
            int bc = t / ROWS;
            const float* base = f1 + (size_t)bc * (W * W) + y * W + si * 4;

            float sum[4] = {0, 0, 0, 0}, sq[4] = {0, 0, 0, 0};
            float sa[4] = {0, 0, 0, 0}, sc[4] = {0, 0, 0, 0};
#pragma unroll
            for (int a = 0; a < 5; ++a) {
                const float* r = base + a * W;
                float4 u = *(const float4*)r;        // 16B-aligned
                float4 v = *(const float4*)(r + 4);
                float p[8] = {u.x, u.y, u.z, u.w, v.x, v.y, v.z, v.w};
                float pre[8], prq[8];
                pre[0] = p[0]; prq[0] = p[0] * p[0];
#pragma unroll
                for (int i = 1; i < 8; ++i) {
                    pre[i] = pre[i - 1] + p[i];
                    prq[i] = prq[i - 1] + p[i] * p[i];
                }
                float aw = (float)(a - 2);
#pragma unroll
                for (int j = 0; j < 4; ++j) {
                    float rs = (j == 0) ? pre[4] : pre[j + 4] - pre[j - 1];
                    float rq = (j == 0) ? prq[4] : prq[j + 4] - prq[j - 1];
                    float rc = (p[j + 3] - p[j + 1]) + 2.f * (p[j + 4] - p[j]);
                    sum[j] += rs; sq[j] += rq; sa[j] += aw * rs; sc[j] += rc;
                }
            }
#pragma unroll
            for (int j = 0; j < 4; ++j)
                acc += sq[j] - sum[j] * sum[j] * invk2
                     - (sa[j] * sa[j] + sc[j] * sc[j]) * invS;
        }
        acc *= 1.0f / (32.0f * 252.0f * 252.0f);
    }

    // block reduction (branch above is block-uniform, so all threads arrive)
    for (int off = 32; off > 0; off >>= 1) acc += __shfl_down(acc, off);
    __shared__ float red[4];
    int lane = threadIdx.x & 63;
    int wid  = threadIdx.x >> 6;
    if (lane == 0) red[wid] = acc;
    __syncthreads();
    if (threadIdx.x == 0)
        atomicAdd(out, red[0] + red[1] + red[2] + red[3]);
}

extern "C" void kernel_launch(void* const* d_in, const int* in_sizes, int n_in,
                              void* d_out, int out_size, void* d_ws, size_t ws_size,
                              hipStream_t stream) {
    const float* flow0 = (const float*)d_in[0];   // (32, 2, 128, 128)
    const float* flow1 = (const float*)d_in[1];   // (32, 2, 256, 256)
    float* out = (float*)d_out;

    hipMemsetAsync(out, 0, sizeof(float), stream);
    fused_affine_loss_kernel<<<NB0 + NB1, 256, 0, stream>>>(flow0, flow1, out);
}